// Round 14
// baseline (39.154 us; speedup 1.0000x reference)
//
#include <hip/hip_runtime.h>
#include <hip/hip_bf16.h>
#include <math.h>

// Problem constants
#define BB 2
#define HH 64
#define WW 64
#define DIMC 128
#define NH 4
#define HD 32
#define KS 7
#define DIL 2
#define NPIX (BB * HH * WW)         // 8192 rows
#define SCALE 0.17677669529663687f  // 32^-0.5

typedef short bf16x8 __attribute__((ext_vector_type(8)));
typedef float f32x4  __attribute__((ext_vector_type(4)));

__device__ __forceinline__ short bf16r(float f) {
    union { float f; unsigned u; } x; x.f = f;
    unsigned r = x.u + 0x7FFF + ((x.u >> 16) & 1);  // RNE
    return (short)(r >> 16);
}
__device__ __forceinline__ float uasf(unsigned u) {
    union { unsigned u; float f; } x; x.u = u; return x.f;
}

// Stage a 128x128 f32 weight matrix (row=k, col=c) into LDS as transposed
// bf16 [c][k], pitch 136 shorts (272B rows: b128-aligned, ~2-way read banks).
// 16 coalesced float4 loads + 64 b16 scatter writes per thread (256 thr).
__device__ __forceinline__ void stage_wT(const float* __restrict__ W,
                                         short* __restrict__ Wls, int t)
{
#pragma unroll
    for (int e = 0; e < 16; ++e) {
        const int idx4 = e * 256 + t;            // float4 index
        const float4 w = *(const float4*)(W + idx4 * 4);
        const int k = idx4 >> 5;                 // 128 floats per k-row
        const int c = (idx4 & 31) * 4;
        Wls[(c + 0) * 136 + k] = bf16r(w.x);
        Wls[(c + 1) * 136 + k] = bf16r(w.y);
        Wls[(c + 2) * 136 + k] = bf16r(w.z);
        Wls[(c + 3) * 136 + k] = bf16r(w.w);
    }
}

// ---------------------------------------------------------------------------
// qkv_mfma v2: block-local W staging (LDS bf16 transposed) + MFMA projection.
// Grid (256, 3), 256 thr. Block = 32 rows; wave = 16 rows x 64 cols.
// ---------------------------------------------------------------------------
__global__ __launch_bounds__(256) void qkv_mfma(
    const float* __restrict__ q, const float* __restrict__ k,
    const float* __restrict__ v,
    const float* __restrict__ Wq, const float* __restrict__ Wk,
    const float* __restrict__ Wv,
    const float* __restrict__ bq, const float* __restrict__ bk,
    const float* __restrict__ bv,
    float* __restrict__ qh, short* __restrict__ khb, short* __restrict__ vhb)
{
    __shared__ short Wls[128 * 136];   // 34,816 B

    const int z = blockIdx.y;
    const float* X    = (z == 0) ? q  : (z == 1) ? k  : v;
    const float* W    = (z == 0) ? Wq : (z == 1) ? Wk : Wv;
    const float* bias = (z == 0) ? bq : (z == 1) ? bk : bv;

    const int t    = threadIdx.x;
    stage_wT(W, Wls, t);

    const int wv   = t >> 6;
    const int lane = t & 63;
    const int lr   = lane & 15;
    const int lg   = lane >> 4;
    const int row0 = blockIdx.x * 32 + (wv & 1) * 16;
    const int col0 = (wv >> 1) * 64;

    // A fragments (global f32 -> bf16 pack) while staging writes drain
    const float* xrow = X + (size_t)(row0 + lr) * 128 + lg * 8;
    bf16x8 a[4];
#pragma unroll
    for (int kk = 0; kk < 4; ++kk) {
        const float4 x0 = *(const float4*)(xrow + kk * 32);
        const float4 x1 = *(const float4*)(xrow + kk * 32 + 4);
        bf16x8 av;
        av[0] = bf16r(x0.x); av[1] = bf16r(x0.y);
        av[2] = bf16r(x0.z); av[3] = bf16r(x0.w);
        av[4] = bf16r(x1.x); av[5] = bf16r(x1.y);
        av[6] = bf16r(x1.z); av[7] = bf16r(x1.w);
        a[kk] = av;
    }

    __syncthreads();

    // B fragments from LDS
    bf16x8 bfr[16];
#pragma unroll
    for (int nt = 0; nt < 4; ++nt) {
        const short* wrow = Wls + (col0 + nt * 16 + lr) * 136 + lg * 8;
#pragma unroll
        for (int kk = 0; kk < 4; ++kk)
            bfr[nt * 4 + kk] = *(const bf16x8*)(wrow + kk * 32);
    }

#pragma unroll
    for (int nt = 0; nt < 4; ++nt) {
        const int col = col0 + nt * 16 + lr;
        f32x4 acc = {0.f, 0.f, 0.f, 0.f};
#pragma unroll
        for (int kk = 0; kk < 4; ++kk)
            acc = __builtin_amdgcn_mfma_f32_16x16x32_bf16(a[kk], bfr[nt * 4 + kk], acc, 0, 0, 0);
        const float bc = bias[col];
        if (z == 0) {
#pragma unroll
            for (int jj = 0; jj < 4; ++jj)
                qh[(size_t)(row0 + lg * 4 + jj) * 128 + col] = (acc[jj] + bc) * SCALE;
        } else {
            short* Yb = (z == 1) ? khb : vhb;
#pragma unroll
            for (int jj = 0; jj < 4; ++jj)
                Yb[(size_t)(row0 + lg * 4 + jj) * 128 + col] = bf16r(acc[jj] + bc);
        }
    }
}

// NATTEN edge-index helper (L=64, K=7, dil=2, ns=3).
__device__ __forceinline__ void natten_idx(int i, int& s, int& p)
{
    if (i < 6) {                 // i - ns*dil < 0
        s = i & 1;
        p = 6 - (i >> 1);
    } else if (i >= 58) {        // i + ns*dil >= L  (L%dil==0 -> b=0 path)
        s = 50 + (i & 1);        // a + i%dil - K*dil
        p = (63 - i) >> 1;
    } else {
        s = i - 6;
        p = 3;
    }
}

// ---------------------------------------------------------------------------
// natten_out v7: R9's best S2 (online softmax, 4 lanes/(px,head), uint4 K/V
// global loads) + Wo staged to LDS at entry (hides under S2) + S3 MFMA.
// 512 blocks x 256 thr (16 px/block); XCD-swizzled work id.
// ---------------------------------------------------------------------------
__global__ __launch_bounds__(256) void natten_out(
    const float* __restrict__ qh, const short* __restrict__ khb,
    const short* __restrict__ vhb, const float* __restrict__ rpb,
    const float* __restrict__ Wo, const float* __restrict__ bo,
    float* __restrict__ out)
{
    __shared__ short WoT[128 * 136];   // 34,816 B
    __shared__ short attS[16][136];    //  4,352 B

    const int blk  = blockIdx.x;
    const int work = (blk & 7) * 64 + (blk >> 3);   // bijective (512 = 8*64)
    const int t    = threadIdx.x;

    stage_wT(Wo, WoT, t);   // writes drain before the pre-S3 barrier

    // ---------------- S2: neighborhood attention (R9, online) ---------------
    {
        const int lane4 = t & 3;
        const int n   = (t >> 2) & 3;
        const int p   = t >> 4;            // 0..15
        const int g   = work * 16 + p;     // < 8192
        const int j   = g & 63;
        const int i   = (g >> 6) & 63;
        const int b   = g >> 12;

        int si, pi0, sj, pj0;
        natten_idx(i, si, pi0);
        natten_idx(j, sj, pj0);

        const int coff = n * 32 + lane4 * 8;
        const size_t pixb = (size_t)(b * 4096 + i * 64 + j);
        const float4 q0 = *(const float4*)(qh + pixb * 128 + coff);
        const float4 q1 = *(const float4*)(qh + pixb * 128 + coff + 4);

        const float* rp = rpb + n * 169;

        float m = -1e30f, l = 0.0f;
        float o[8] = {0.f, 0.f, 0.f, 0.f, 0.f, 0.f, 0.f, 0.f};

#pragma unroll
        for (int ki = 0; ki < 7; ++ki) {
            const int iy = si + 2 * ki;
            const size_t rowbase = ((size_t)(b * 4096 + iy * 64)) * 128 + coff;
            const float* rrow = rp + (pi0 + ki) * 13 + pj0;

            float d[7];
#pragma unroll
            for (int kj = 0; kj < 7; ++kj) {
                const int ix = sj + 2 * kj;
                const uint4 kv = *(const uint4*)(khb + rowbase + (size_t)ix * 128);
                float dd =      q0.x * uasf(kv.x << 16);
                dd = fmaf(q0.y, uasf(kv.x & 0xFFFF0000u), dd);
                dd = fmaf(q0.z, uasf(kv.y << 16), dd);
                dd = fmaf(q0.w, uasf(kv.y & 0xFFFF0000u), dd);
                dd = fmaf(q1.x, uasf(kv.z << 16), dd);
                dd = fmaf(q1.y, uasf(kv.z & 0xFFFF0000u), dd);
                dd = fmaf(q1.z, uasf(kv.w << 16), dd);
                dd = fmaf(q1.w, uasf(kv.w & 0xFFFF0000u), dd);
                d[kj] = dd;
            }
#pragma unroll
            for (int kj = 0; kj < 7; ++kj) d[kj] += __shfl_xor(d[kj], 1);
#pragma unroll
            for (int kj = 0; kj < 7; ++kj) d[kj] += __shfl_xor(d[kj], 2);
#pragma unroll
            for (int kj = 0; kj < 7; ++kj) d[kj] += rrow[kj];

            const float g01 = fmaxf(d[0], d[1]);
            const float g23 = fmaxf(d[2], d[3]);
            const float g45 = fmaxf(d[4], d[5]);
            const float gm  = fmaxf(fmaxf(g01, g23), fmaxf(g45, d[6]));
            const float mn  = fmaxf(m, gm);
            const float corr = __expf(m - mn);
            m = mn;
            l *= corr;
#pragma unroll
            for (int e = 0; e < 8; ++e) o[e] *= corr;

#pragma unroll
            for (int kj = 0; kj < 7; ++kj) {
                const float pe = __expf(d[kj] - m);
                d[kj] = pe;
                l += pe;
            }

#pragma unroll
            for (int kj = 0; kj < 7; ++kj) {
                const int ix = sj + 2 * kj;
                const uint4 vv = *(const uint4*)(vhb + rowbase + (size_t)ix * 128);
                const float pe = d[kj];
                o[0] = fmaf(pe, uasf(vv.x << 16),          o[0]);
                o[1] = fmaf(pe, uasf(vv.x & 0xFFFF0000u),  o[1]);
                o[2] = fmaf(pe, uasf(vv.y << 16),          o[2]);
                o[3] = fmaf(pe, uasf(vv.y & 0xFFFF0000u),  o[3]);
                o[4] = fmaf(pe, uasf(vv.z << 16),          o[4]);
                o[5] = fmaf(pe, uasf(vv.z & 0xFFFF0000u),  o[5]);
                o[6] = fmaf(pe, uasf(vv.w << 16),          o[6]);
                o[7] = fmaf(pe, uasf(vv.w & 0xFFFF0000u),  o[7]);
            }
        }

        const float inv = 1.0f / l;
        bf16x8 ow;
#pragma unroll
        for (int e = 0; e < 8; ++e) ow[e] = bf16r(o[e] * inv);
        *(bf16x8*)&attS[p][coff] = ow;
    }

    __syncthreads();

    // ---------------- S3: out projection (Wo from LDS) ----------------------
    {
        const int wv   = t >> 6;
        const int lane = t & 63;
        const int lr   = lane & 15;
        const int lg   = lane >> 4;
        const int col0 = wv * 32;

        bf16x8 bfr[8];
#pragma unroll
        for (int nt = 0; nt < 2; ++nt) {
            const short* wrow = WoT + (col0 + nt * 16 + lr) * 136 + lg * 8;
#pragma unroll
            for (int kk = 0; kk < 4; ++kk)
                bfr[nt * 4 + kk] = *(const bf16x8*)(wrow + kk * 32);
        }
        bf16x8 a[4];
#pragma unroll
        for (int kk = 0; kk < 4; ++kk)
            a[kk] = *(const bf16x8*)&attS[lr][kk * 32 + lg * 8];

#pragma unroll
        for (int nt = 0; nt < 2; ++nt) {
            const int col = col0 + nt * 16 + lr;
            f32x4 acc = {0.f, 0.f, 0.f, 0.f};
#pragma unroll
            for (int kk = 0; kk < 4; ++kk)
                acc = __builtin_amdgcn_mfma_f32_16x16x32_bf16(a[kk], bfr[nt * 4 + kk], acc, 0, 0, 0);
            const float bc = bo[col];
#pragma unroll
            for (int jj = 0; jj < 4; ++jj)
                out[(size_t)(work * 16 + lg * 4 + jj) * 128 + col] = acc[jj] + bc;
        }
    }
}

// ---------------------------------------------------------------------------
extern "C" void kernel_launch(void* const* d_in, const int* in_sizes, int n_in,
                              void* d_out, int out_size, void* d_ws, size_t ws_size,
                              hipStream_t stream)
{
    const float* q   = (const float*)d_in[0];
    const float* k   = (const float*)d_in[1];
    const float* v   = (const float*)d_in[2];
    const float* Wq  = (const float*)d_in[3];
    const float* bq  = (const float*)d_in[4];
    const float* Wk  = (const float*)d_in[5];
    const float* bk  = (const float*)d_in[6];
    const float* Wv  = (const float*)d_in[7];
    const float* bv  = (const float*)d_in[8];
    const float* rpb = (const float*)d_in[9];
    const float* Wo  = (const float*)d_in[10];
    const float* bo  = (const float*)d_in[11];

    float* ws   = (float*)d_ws;
    float* qh   = ws;                                   // f32 [8192][128]  (4 MB)
    short* khb  = (short*)(ws + (size_t)NPIX * 128);    // bf16 [8192][128] (2 MB)
    short* vhb  = khb + (size_t)NPIX * 128;             // bf16 (2 MB)
    float* out  = (float*)d_out;

    hipLaunchKernelGGL(qkv_mfma, dim3(256, 3), dim3(256), 0, stream,
                       q, k, v, Wq, Wk, Wv, bq, bk, bv, qh, khb, vhb);

    hipLaunchKernelGGL(natten_out, dim3(512), dim3(256), 0, stream,
                       qh, khb, vhb, rpb, Wo, bo, out);
}